// Round 5
// baseline (1374.364 us; speedup 1.0000x reference)
//
#include <hip/hip_runtime.h>
#include <hip/hip_bf16.h>

using short4v  = __attribute__((ext_vector_type(4))) short;
using short8   = __attribute__((ext_vector_type(8))) short;
using floatx4  = __attribute__((ext_vector_type(4))) float;
using floatx16 = __attribute__((ext_vector_type(16))) float;
using u16      = unsigned short;
using u32      = unsigned int;

#define NBATCH   4
#define SEQ      4096
#define DMODEL   1024
#define NTHREADS 512
#define SCALE    0.03125f   // 1/sqrt(1024)
#define NMKT     16         // mega-kv-tiles of 256 rows
#define NCHB     512        // 32KB chunks per batch = NMKT * (16 K + 16 V)

__device__ __forceinline__ u16 f2bf(float x) {
  union { __hip_bfloat16 h; u16 u; } cv;
  cv.h = __float2bfloat16(x);
  return cv.u;
}

__device__ __forceinline__ void gload16(const void* g, void* l) {
  __builtin_amdgcn_global_load_lds(
      (const __attribute__((address_space(1))) u32*)g,
      (__attribute__((address_space(3))) u32*)l, 16, 0, 0);
}

// Conflict-free fragment load: two ds_read_b64 at XOR'd 8B slots.
// off = byte offset within row (multiple of 16), swb = ((row&15)<<3).
// 32 rows spread over all 16 bank-pairs -> <=2-way aliasing (free, m136).
__device__ __forceinline__ short8 ld8(const char* rowbase, u32 off, u32 swb) {
  short4v lo = *(const short4v*)(rowbase + ((off ^ swb)));
  short4v hi = *(const short4v*)(rowbase + ((off ^ swb) ^ 8));
  short8 r;
  r[0] = lo[0]; r[1] = lo[1]; r[2] = lo[2]; r[3] = lo[3];
  r[4] = hi[0]; r[5] = hi[1]; r[6] = hi[2]; r[7] = hi[3];
  return r;
}

// ============================ pre-pass kernels ==============================
// Workspace per batch: 512 chunks x 32KB, stream order per mkt (256 kv rows):
//   chunks 0..15  : K  [256 kv][64 d]  (d-range j*64), pre-scaled by SCALE
//   chunks 16..31 : V^T [256 d][64 kv] (chunk 16+kvq*4+dsl: kv kvq*64, d dsl*256)
// Rows are 128B; u16 element c stored at c ^ ((row&15)<<2) (8B granule) so the
// main kernel stages LINEARLY via global_load_lds and reads via ld8().
__global__ __launch_bounds__(256)
void conv_k(const float* __restrict__ Kg, u16* __restrict__ Wws) {
  const int s = blockIdx.x, b = blockIdx.y, t = threadIdx.x;
  const int d4 = t << 2;
  float4 v = *(const float4*)&Kg[((size_t)(b * SEQ + s)) * DMODEL + d4];
  ushort4 pk = { f2bf(v.x * SCALE), f2bf(v.y * SCALE),
                 f2bf(v.z * SCALE), f2bf(v.w * SCALE) };
  const int mkt = s >> 8, kv = s & 255, j = d4 >> 6, c = d4 & 63;
  const size_t chunk = (size_t)((b * NMKT + mkt) * 32 + j);
  *(ushort4*)&Wws[chunk * 16384 + kv * 64 + (c ^ ((kv & 15) << 2))] = pk;
}

__global__ __launch_bounds__(256)
void conv_v(const float* __restrict__ Vg, u16* __restrict__ Wws) {
  __shared__ u16 sT[32][260];
  const int b = blockIdx.z, dsl = blockIdx.y;
  const int s0 = blockIdx.x * 32;
  const int mkt = s0 >> 8, kvq = (s0 >> 6) & 3, kvhi = s0 & 32;
  const int t = threadIdx.x;
  #pragma unroll
  for (int i = 0; i < 8; i++) {              // 32 s-rows x 256 d f32
    const int e = t + i * 256;
    const int r = e >> 6, c4 = (e & 63) << 2;
    float4 v = *(const float4*)&Vg[((size_t)(b * SEQ + s0 + r)) * DMODEL + dsl * 256 + c4];
    ushort4 pk = { f2bf(v.x), f2bf(v.y), f2bf(v.z), f2bf(v.w) };
    *(ushort4*)&sT[r][c4] = pk;
  }
  __syncthreads();
  const size_t chunk = (size_t)((b * NMKT + mkt) * 32 + 16 + kvq * 4 + dsl);
  #pragma unroll
  for (int i = 0; i < 8; i++) {              // 256 d-rows x 32 kv u16
    const int e = t + i * 256;
    const int dr = e >> 3, kv4 = (e & 7) << 2;
    ushort4 pk;
    pk.x = sT[kv4 + 0][dr]; pk.y = sT[kv4 + 1][dr];
    pk.z = sT[kv4 + 2][dr]; pk.w = sT[kv4 + 3][dr];
    const int col = (kvhi + kv4) ^ ((dr & 15) << 2);
    *(ushort4*)&Wws[chunk * 16384 + dr * 64 + col] = pk;
  }
}

// ============================== main kernel =================================
// R4 structure (verified) + (a) all fragment reads via 2x ds_read_b64 with
// (row&15) 8B-XOR swizzle (conflict-free), (b) Q fragments for j=0..3 hoisted
// into 64 VGPRs (25% less Q LDS re-read traffic).
__global__ __launch_bounds__(NTHREADS, 2)
void fa_fwd5(const float* __restrict__ Qg,
             const u16* __restrict__ Wws,
             float* __restrict__ Og) {
  __shared__ __align__(16) u16 sQ[32 * 1024];   // 64 KB, rows 2048B
  __shared__ __align__(16) u16 sB[2][16384];    // 2 x 32 KB staging
  __shared__ __align__(16) u16 sP[32 * 256];    // 16 KB, P[q][kv]
  __shared__ float sMx[8][32], sLs[8][32];

  const int tid  = threadIdx.x;
  const int w    = tid >> 6;
  const int lane = tid & 63;
  const int q    = lane & 31;     // this lane's q-row (C/D col for both GEMMs)
  const int h    = lane >> 5;

  // XCD-contiguous swizzle: each XCD gets 64 consecutive wg (same batch).
  const int wg    = (blockIdx.x & 7) * 64 + (blockIdx.x >> 3);
  const int batch = wg >> 7;
  const int q0    = (wg & 127) * 32;

  const char* WB = (const char*)Wws + (size_t)batch * NCHB * 32768;

  #define ISSUE(CIDX, BUF) do {                                   \
    const char* g_ = WB + (size_t)(CIDX) * 32768 + tid * 16;      \
    char* lb_ = (char*)(BUF) + ((tid & ~63) << 4);                \
    gload16(g_,         lb_);                                     \
    gload16(g_ +  8192, lb_ +  8192);                             \
    gload16(g_ + 16384, lb_ + 16384);                             \
    gload16(g_ + 24576, lb_ + 24576);                             \
  } while (0)

  ISSUE(0, sB[0]);

  // ---- Q prologue: 32x1024 f32 -> bf16 LDS once (rows swizzled (r&15)<<2) ----
  const size_t qbase = (size_t)(batch * SEQ + q0) * DMODEL;
  #pragma unroll
  for (int i = 0; i < 16; i++) {
    const int e   = tid + i * NTHREADS;
    const int row = e >> 8;
    const int c4  = (e & 255) << 2;
    float4 v = *(const float4*)&Qg[qbase + (size_t)row * DMODEL + c4];
    ushort4 pk = { f2bf(v.x), f2bf(v.y), f2bf(v.z), f2bf(v.w) };
    *(ushort4*)&sQ[row * 1024 + (c4 ^ ((row & 15) << 2))] = pk;
  }

  // ---- register-Q for j=0..3: lane's own B-fragments, straight from global ----
  short8 qreg[4][4];   // 64 VGPRs; indices always compile-time (rule #20)
  {
    const float* Qrow = Qg + (size_t)(batch * SEQ + q0 + q) * DMODEL + h * 8;
    #pragma unroll
    for (int j = 0; j < 4; ++j)
      #pragma unroll
      for (int t = 0; t < 4; ++t) {
        const float* p = Qrow + j * 64 + t * 16;
        float4 u0 = *(const float4*)p;
        float4 u1 = *(const float4*)(p + 4);
        short8 r;
        r[0] = (short)f2bf(u0.x); r[1] = (short)f2bf(u0.y);
        r[2] = (short)f2bf(u0.z); r[3] = (short)f2bf(u0.w);
        r[4] = (short)f2bf(u1.x); r[5] = (short)f2bf(u1.y);
        r[6] = (short)f2bf(u1.z); r[7] = (short)f2bf(u1.w);
        qreg[j][t] = r;
      }
  }
  __syncthreads();   // sQ visible; drains chunk 0 + qreg loads (prologue only)

  floatx16 acc[4];
  #pragma unroll
  for (int d = 0; d < 4; d++) acc[d] = (floatx16)0.0f;
  floatx16 sacc = (floatx16)0.0f;
  float m_prev = -1e30f, l_prev = 0.0f;

  u32 gnext = 1;     // next chunk to issue
  int par   = 0;     // buffer parity of the chunk being computed

  const u32 swb   = (u32)(q & 15) << 3;       // byte XOR for all fragment reads
  const u32 rbase = (u32)(w * 32 + q) * 128;  // A-frag row base in chunk
  const u32 h16   = (u32)h * 16;
  const u32 qrow  = (u32)q * 2048;            // sQ byte row base
  const u32 prow  = (u32)q * 512;             // sP byte row base

  // phase top: wait for current chunk (issued 1 phase ago), barrier,
  // issue the next chunk into the buffer freed by the previous phase.
  #define PHASE_TOP() do {                                        \
    asm volatile("s_waitcnt vmcnt(0)" ::: "memory");              \
    __builtin_amdgcn_s_barrier();                                 \
    ISSUE(gnext & (NCHB - 1), sB[gnext & 1]);                     \
    par = (int)(gnext & 1) ^ 1;                                   \
    gnext++;                                                      \
  } while (0)

  for (int mkt = 0; mkt < NMKT; ++mkt) {
    // ---------------- S^T = K Q^T over d=1024 (16 K-phases) ----------------
    // j = 0..3: Q from registers (no LDS bq reads)
    #pragma unroll
    for (int j = 0; j < 4; ++j) {
      PHASE_TOP();
      const char* cb = (const char*)sB[par];
      short8 a[4];
      #pragma unroll
      for (int t = 0; t < 4; ++t)
        a[t] = ld8(cb + rbase, (u32)t * 32 + h16, swb);
      __builtin_amdgcn_s_setprio(1);
      #pragma unroll
      for (int t = 0; t < 4; ++t)
        sacc = __builtin_amdgcn_mfma_f32_32x32x16_bf16(a[t], qreg[j][t], sacc, 0, 0, 0);
      __builtin_amdgcn_s_setprio(0);
    }
    // j = 4..15: Q from LDS
    for (int j = 4; j < 16; ++j) {
      PHASE_TOP();
      const char* cb = (const char*)sB[par];
      const char* qp = (const char*)sQ + qrow;
      short8 a[4], bq[4];
      #pragma unroll
      for (int t = 0; t < 4; ++t) {
        a[t]  = ld8(cb + rbase, (u32)t * 32 + h16, swb);
        bq[t] = ld8(qp, (u32)j * 128 + t * 32 + h16, swb);
      }
      __builtin_amdgcn_s_setprio(1);
      #pragma unroll
      for (int t = 0; t < 4; ++t)
        sacc = __builtin_amdgcn_mfma_f32_32x32x16_bf16(a[t], bq[t], sacc, 0, 0, 0);
      __builtin_amdgcn_s_setprio(0);
    }

    // ---------------- in-register online softmax (R3/R4-verified) ----------------
    float mx = sacc[0];
    #pragma unroll
    for (int i = 1; i < 16; i++) mx = fmaxf(mx, sacc[i]);
    mx = fmaxf(mx, __shfl_xor(mx, 32));
    if (lane < 32) sMx[w][lane] = mx;
    __syncthreads();
    float m_kt = sMx[0][q];
    #pragma unroll
    for (int w2 = 1; w2 < 8; ++w2) m_kt = fmaxf(m_kt, sMx[w2][q]);
    const float m_new = fmaxf(m_prev, m_kt);
    const float al = __expf(m_prev - m_new);   // 0 on first tile
    m_prev = m_new;
    float sum = 0.0f;
    #pragma unroll
    for (int i = 0; i < 16; i++) {
      float p = __expf(sacc[i] - m_new);
      sacc[i] = p;
      sum += p;
    }
    sum += __shfl_xor(sum, 32);
    if (lane < 32) sLs[w][lane] = sum;
    // P -> bf16 -> sP[q][kv]; lane's C rows: kv_local = (r&3)+8*(r>>2)+4h
    #pragma unroll
    for (int g = 0; g < 4; ++g) {
      ushort4 pk = { f2bf(sacc[4*g+0]), f2bf(sacc[4*g+1]),
                     f2bf(sacc[4*g+2]), f2bf(sacc[4*g+3]) };
      const u32 kvb = (u32)(w * 32 + g * 8 + h * 4);
      *(ushort4*)&sP[q * 256 + (kvb ^ ((q & 15) << 2))] = pk;
    }
    #pragma unroll
    for (int d = 0; d < 4; d++)
      #pragma unroll
      for (int i = 0; i < 16; i++) acc[d][i] *= al;
    __syncthreads();   // sP + sLs ready
    float l_kt = sLs[0][q];
    #pragma unroll
    for (int w2 = 1; w2 < 8; ++w2) l_kt += sLs[w2][q];
    l_prev = l_prev * al + l_kt;
    sacc = (floatx16)0.0f;

    // ---------------- O^T += V^T P^T (16 V-phases: 4 kvq x 4 dsl) ------------
    for (int kvq = 0; kvq < 4; ++kvq) {
      short8 pb[4];   // P B-frags, reused across the 4 dsl phases
      #pragma unroll
      for (int t = 0; t < 4; ++t)
        pb[t] = ld8((const char*)sP + prow, (u32)kvq * 128 + t * 32 + h16, swb);
      #pragma unroll
      for (int dsl = 0; dsl < 4; ++dsl) {
        PHASE_TOP();
        const char* cb = (const char*)sB[par];
        short8 va[4];
        #pragma unroll
        for (int t = 0; t < 4; ++t)
          va[t] = ld8(cb + rbase, (u32)t * 32 + h16, swb);
        __builtin_amdgcn_s_setprio(1);
        #pragma unroll
        for (int t = 0; t < 4; ++t)
          acc[dsl] = __builtin_amdgcn_mfma_f32_32x32x16_bf16(va[t], pb[t], acc[dsl], 0, 0, 0);
        __builtin_amdgcn_s_setprio(0);
      }
    }
  }

  asm volatile("s_waitcnt vmcnt(0)" ::: "memory");  // drain last wrap-issue

  // ---------------- epilogue: O = acc^T / l (verified) ----------------
  const float rinv = 1.0f / l_prev;
  const size_t orow = (size_t)(batch * SEQ + q0 + q) * DMODEL;
  #pragma unroll
  for (int dsl = 0; dsl < 4; ++dsl) {
    #pragma unroll
    for (int g = 0; g < 4; ++g) {
      float4 o = { acc[dsl][4*g+0]*rinv, acc[dsl][4*g+1]*rinv,
                   acc[dsl][4*g+2]*rinv, acc[dsl][4*g+3]*rinv };
      *(float4*)&Og[orow + dsl * 256 + w * 32 + g * 8 + h * 4] = o;
    }
  }
  #undef PHASE_TOP
  #undef ISSUE
}

// ===================== fallback (verified round-1 kernel) ====================
__global__ __launch_bounds__(NTHREADS, 2)
void fa_fwd_fb(const float* __restrict__ Qg,
               const float* __restrict__ Kg,
               const float* __restrict__ Vg,
               float* __restrict__ Og) {
  __shared__ __align__(16) u16   sQ[32][1032];
  __shared__ __align__(16) u16   sK[64][264];
  __shared__ __align__(16) float sS[32][66];
  __shared__ __align__(16) u16   sP[32][72];
  __shared__ float sM[32], sL[32], sAl[32];

  const int tid = threadIdx.x, w = tid >> 6, lane = tid & 63;
  const int quad = lane >> 4, l15 = lane & 15;
  const int batch = blockIdx.y, q0 = blockIdx.x * 32;
  const size_t qbase  = (size_t)(batch * SEQ + q0) * DMODEL;
  const size_t kvbase = (size_t)batch * SEQ * DMODEL;
  if (tid < 32) { sM[tid] = -1e30f; sL[tid] = 0.0f; }
  #pragma unroll
  for (int i = 0; i < 16; i++) {
    const int e = tid + i * NTHREADS, row = e >> 8, c4 = (e & 255) << 2;
    float4 v = *(const float4*)&Qg[qbase + (size_t)row * DMODEL + c4];
    ushort4 pk = { f2bf(v.x), f2bf(v.y), f2bf(v.z), f2bf(v.w) };
    *(ushort4*)&sQ[row][c4] = pk;
  }
  floatx4 acc[2][8];
  #pragma unroll
  for (int rt = 0; rt < 2; rt++)
    #pragma unroll
    for (int ci = 0; ci < 8; ci++) acc[rt][ci] = (floatx4)0.0f;
  const int wr = w >> 2, wc = w & 3;
  for (int kt = 0; kt < SEQ / 64; kt++) {
    floatx4 sacc = (floatx4)0.0f;
    for (int dc = 0; dc < 4; dc++) {
      __syncthreads();
      #pragma unroll
      for (int i = 0; i < 8; i++) {
        const int e = tid + i * NTHREADS, row = e >> 6, c4 = (e & 63) << 2;
        float4 v = *(const float4*)&Kg[kvbase + (size_t)(kt * 64 + row) * DMODEL + dc * 256 + c4];
        ushort4 pk = { f2bf(v.x), f2bf(v.y), f2bf(v.z), f2bf(v.w) };
        *(ushort4*)&sK[row][c4] = pk;
      }
      __syncthreads();
      #pragma unroll
      for (int ks = 0; ks < 8; ks++) {
        short8 av = *(const short8*)&sQ[wr * 16 + l15][dc * 256 + ks * 32 + quad * 8];
        short8 bv = *(const short8*)&sK[wc * 16 + l15][ks * 32 + quad * 8];
        sacc = __builtin_amdgcn_mfma_f32_16x16x32_bf16(av, bv, sacc, 0, 0, 0);
      }
    }
    #pragma unroll
    for (int r = 0; r < 4; r++)
      sS[wr * 16 + quad * 4 + r][wc * 16 + l15] = sacc[r];
    __syncthreads();
    {
      const int row = tid >> 4, c0 = tid & 15;
      float v0 = sS[row][c0] * SCALE, v1 = sS[row][c0 + 16] * SCALE;
      float v2 = sS[row][c0 + 32] * SCALE, v3 = sS[row][c0 + 48] * SCALE;
      float mx = fmaxf(fmaxf(v0, v1), fmaxf(v2, v3));
      #pragma unroll
      for (int off = 8; off >= 1; off >>= 1) mx = fmaxf(mx, __shfl_xor(mx, off, 16));
      const float m_old = sM[row], m_new = fmaxf(m_old, mx);
      const float p0 = __expf(v0 - m_new), p1 = __expf(v1 - m_new);
      const float p2 = __expf(v2 - m_new), p3 = __expf(v3 - m_new);
      sP[row][c0] = f2bf(p0); sP[row][c0 + 16] = f2bf(p1);
      sP[row][c0 + 32] = f2bf(p2); sP[row][c0 + 48] = f2bf(p3);
      float sum = p0 + p1 + p2 + p3;
      #pragma unroll
      for (int off = 8; off >= 1; off >>= 1) sum += __shfl_xor(sum, off, 16);
      if (c0 == 0) {
        const float al = __expf(m_old - m_new);
        sAl[row] = al; sM[row] = m_new; sL[row] = sL[row] * al + sum;
      }
    }
    __syncthreads();
    float alv[2][4];
    #pragma unroll
    for (int rt = 0; rt < 2; rt++)
      #pragma unroll
      for (int r = 0; r < 4; r++) alv[rt][r] = sAl[rt * 16 + quad * 4 + r];
    #pragma unroll
    for (int rt = 0; rt < 2; rt++)
      #pragma unroll
      for (int ci = 0; ci < 8; ci++)
        #pragma unroll
        for (int r = 0; r < 4; r++) acc[rt][ci][r] *= alv[rt][r];
    #pragma unroll
    for (int ks = 0; ks < 2; ks++) {
      short8 a0 = *(const short8*)&sP[l15][ks * 32 + quad * 8];
      short8 a1 = *(const short8*)&sP[16 + l15][ks * 32 + quad * 8];
      #pragma unroll
      for (int ci = 0; ci < 8; ci++) {
        const int col = ((ci << 3) + w) * 16 + l15;
        const float* vp = Vg + kvbase + (size_t)(kt * 64 + ks * 32 + quad * 8) * DMODEL + col;
        short8 bv;
        #pragma unroll
        for (int j = 0; j < 8; j++) bv[j] = (short)f2bf(vp[(size_t)j * DMODEL]);
        acc[0][ci] = __builtin_amdgcn_mfma_f32_16x16x32_bf16(a0, bv, acc[0][ci], 0, 0, 0);
        acc[1][ci] = __builtin_amdgcn_mfma_f32_16x16x32_bf16(a1, bv, acc[1][ci], 0, 0, 0);
      }
    }
  }
  float linv[2][4];
  #pragma unroll
  for (int rt = 0; rt < 2; rt++)
    #pragma unroll
    for (int r = 0; r < 4; r++) linv[rt][r] = 1.0f / sL[rt * 16 + quad * 4 + r];
  #pragma unroll
  for (int rt = 0; rt < 2; rt++)
    #pragma unroll
    for (int ci = 0; ci < 8; ci++) {
      const int col = ((ci << 3) + w) * 16 + l15;
      #pragma unroll
      for (int r = 0; r < 4; r++) {
        const int row = q0 + rt * 16 + quad * 4 + r;
        Og[(size_t)(batch * SEQ + row) * DMODEL + col] = acc[rt][ci][r] * linv[rt][r];
      }
    }
}

extern "C" void kernel_launch(void* const* d_in, const int* in_sizes, int n_in,
                              void* d_out, int out_size, void* d_ws, size_t ws_size,
                              hipStream_t stream) {
  const float* Q = (const float*)d_in[0];
  const float* K = (const float*)d_in[1];
  const float* V = (const float*)d_in[2];
  float* O = (float*)d_out;
  const size_t wneed = (size_t)NBATCH * NCHB * 32768;   // 64 MB
  if (ws_size >= wneed) {
    u16* Wws = (u16*)d_ws;
    conv_k<<<dim3(SEQ, NBATCH), 256, 0, stream>>>(K, Wws);
    conv_v<<<dim3(SEQ / 32, DMODEL / 256, NBATCH), 256, 0, stream>>>(V, Wws);
    fa_fwd5<<<dim3(512), NTHREADS, 0, stream>>>(Q, Wws, O);
  } else {
    fa_fwd_fb<<<dim3(SEQ / 32, NBATCH), NTHREADS, 0, stream>>>(Q, K, V, O);
  }
}

// Round 6
// 559.450 us; speedup vs baseline: 2.4566x; 2.4566x over previous
//
#include <hip/hip_runtime.h>
#include <hip/hip_bf16.h>

using short8   = __attribute__((ext_vector_type(8))) short;
using floatx4  = __attribute__((ext_vector_type(4))) float;
using floatx16 = __attribute__((ext_vector_type(16))) float;
using u16      = unsigned short;
using u32      = unsigned int;

#define NBATCH   4
#define SEQ      4096
#define DMODEL   1024
#define NTHREADS 512
#define SCALE    0.03125f   // 1/sqrt(1024)
#define NMKT     16         // mega-kv-tiles of 256 rows
#define NCHB     512        // 32KB chunks per batch = NMKT * (16 K + 16 V)

__device__ __forceinline__ u16 f2bf(float x) {
  union { __hip_bfloat16 h; u16 u; } cv;
  cv.h = __float2bfloat16(x);
  return cv.u;
}

// ============================ pre-pass kernels ==============================
// Workspace per batch: 512 chunks x 32KB, sequential stream per mkt:
//   chunks 0..15  : K  (d-range j*64),  chunks 16..31 : V^T (kvq*4+dsl)
// Fragment-order layout: byte = chunk*32768 + w*4096 + t*1024 + lane*16
// (lane = h*32+q), holding exactly the 16B MFMA A-fragment lane (w,t,h,q)
// consumes -> main kernel loads are fully-coalesced global_load_dwordx4,
// straight to VGPRs (NO LDS staging: chunk data has zero cross-wave reuse).
__global__ __launch_bounds__(256)
void conv_k(const float* __restrict__ Kg, u16* __restrict__ Wws) {
  const int s = blockIdx.x, b = blockIdx.y, t = threadIdx.x;
  const int d4 = t << 2;
  float4 v = *(const float4*)&Kg[((size_t)(b * SEQ + s)) * DMODEL + d4];
  ushort4 pk = { f2bf(v.x * SCALE), f2bf(v.y * SCALE),
                 f2bf(v.z * SCALE), f2bf(v.w * SCALE) };
  const int mkt = s >> 8, w = (s >> 5) & 7, q = s & 31;
  const int j = d4 >> 6, dl = d4 & 63;
  const int tq = dl >> 4, h = (dl >> 3) & 1, e = dl & 7;
  const size_t chunk = (size_t)((b * NMKT + mkt) * 32 + j);
  *(ushort4*)&Wws[chunk * 16384 + w * 2048 + tq * 512 + h * 256 + q * 8 + e] = pk;
}

__global__ __launch_bounds__(256)
void conv_v(const float* __restrict__ Vg, u16* __restrict__ Wws) {
  __shared__ u16 sT[32][260];
  const int b = blockIdx.z, dsl = blockIdx.y;
  const int s0 = blockIdx.x * 32;
  const int mkt = s0 >> 8, kvq = (s0 >> 6) & 3, kvhi = s0 & 32;
  const int t = threadIdx.x;
  #pragma unroll
  for (int i = 0; i < 8; i++) {              // 32 s-rows x 256 d f32
    const int e = t + i * 256;
    const int r = e >> 6, c4 = (e & 63) << 2;
    float4 v = *(const float4*)&Vg[((size_t)(b * SEQ + s0 + r)) * DMODEL + dsl * 256 + c4];
    ushort4 pk = { f2bf(v.x), f2bf(v.y), f2bf(v.z), f2bf(v.w) };
    *(ushort4*)&sT[r][c4] = pk;
  }
  __syncthreads();
  const size_t chunk = (size_t)((b * NMKT + mkt) * 32 + 16 + kvq * 4 + dsl);
  #pragma unroll
  for (int i = 0; i < 8; i++) {              // 256 d-rows x 32 kv u16
    const int e = t + i * 256;
    const int dr = e >> 3, kv4 = (e & 7) << 2;
    ushort4 pk;
    pk.x = sT[kv4 + 0][dr]; pk.y = sT[kv4 + 1][dr];
    pk.z = sT[kv4 + 2][dr]; pk.w = sT[kv4 + 3][dr];
    const int kvl = kvhi + kv4;              // kv-local 0..63 within chunk
    const int tq = kvl >> 4, h = (kvl >> 3) & 1, e2 = kvl & 7;
    const int wq = dr >> 5, qq = dr & 31;
    *(ushort4*)&Wws[chunk * 16384 + wq * 2048 + tq * 512 + h * 256 + qq * 8 + e2] = pk;
  }
}

// ============================== main kernel =================================
// R4's verified math (swapped S^T = mfma(K,Q), in-register softmax, sP layout,
// epilogue) with a barrier-free K/V path: fragments load global->VGPR with a
// 4-buffer rotation (load chunk p+3 while computing p; compiler-counted vmcnt,
// ~3-phase latency window). LDS holds only Q (shared) and P. 2 barriers/mkt.
__global__ __launch_bounds__(NTHREADS, 2)
void fa_fwd6(const float* __restrict__ Qg,
             const u16* __restrict__ Wws,
             float* __restrict__ Og) {
  __shared__ __align__(16) u16 sQ[32 * 1024];   // 64 KB, rows 2048B, XOR ((r&7)<<3) elems
  __shared__ __align__(16) u16 sP[32 * 256];    // 16 KB, P[q][kv],  XOR ((q&7)<<3) elems
  __shared__ float sMx[8][32], sLs[8][32];

  const int tid  = threadIdx.x;
  const int w    = tid >> 6;
  const int lane = tid & 63;
  const int q    = lane & 31;     // this lane's q-row (C/D col for both GEMMs)
  const int h    = lane >> 5;

  // XCD-contiguous swizzle: each XCD gets 64 consecutive wg (same batch).
  const int wg    = (blockIdx.x & 7) * 64 + (blockIdx.x >> 3);
  const int batch = wg >> 7;
  const int q0    = (wg & 127) * 32;

  const char* WB = (const char*)Wws + (size_t)batch * NCHB * 32768;
  const u32 fo = (u32)w * 4096 + (u32)lane * 16;   // this lane's fragment slot

  short8 fA0, fA1, fA2, fA3, fB0, fB1, fB2, fB3;
  short8 fC0, fC1, fC2, fC3, fD0, fD1, fD2, fD3;

  #define LOADF(R0, R1, R2, R3, CI) do {                           \
    const char* p_ = WB + (size_t)((u32)(CI) & (NCHB - 1)) * 32768 + fo; \
    R0 = *(const short8*)(p_);                                     \
    R1 = *(const short8*)(p_ + 1024);                              \
    R2 = *(const short8*)(p_ + 2048);                              \
    R3 = *(const short8*)(p_ + 3072);                              \
  } while (0)

  LOADF(fA0, fA1, fA2, fA3, 0);
  LOADF(fB0, fB1, fB2, fB3, 1);
  LOADF(fC0, fC1, fC2, fC3, 2);

  // ---- Q prologue: 32x1024 f32 -> bf16 LDS once, swizzled (R4-verified) ----
  const size_t qbase = (size_t)(batch * SEQ + q0) * DMODEL;
  #pragma unroll
  for (int i = 0; i < 16; i++) {
    const int e   = tid + i * NTHREADS;
    const int row = e >> 8;
    const int c4  = (e & 255) << 2;
    float4 v = *(const float4*)&Qg[qbase + (size_t)row * DMODEL + c4];
    ushort4 pk = { f2bf(v.x), f2bf(v.y), f2bf(v.z), f2bf(v.w) };
    *(ushort4*)&sQ[row * 1024 + (c4 ^ ((row & 7) << 3))] = pk;
  }
  __syncthreads();

  floatx16 acc0 = (floatx16)0.0f, acc1 = (floatx16)0.0f;
  floatx16 acc2 = (floatx16)0.0f, acc3 = (floatx16)0.0f;
  floatx16 sacc = (floatx16)0.0f;
  float m_prev = -1e30f, l_prev = 0.0f;

  const u32 qswz = (u32)(q & 7) << 4;   // byte XOR for sQ/sP reads
  const u32 h16  = (u32)h * 16;
  const u32 qrow = (u32)q * 2048;       // sQ byte row base
  const u32 prow = (u32)q * 512;        // sP byte row base

  #define QK4(A0, A1, A2, A3, J) do {                                         \
    const char* qp_ = (const char*)sQ + qrow;                                 \
    short8 b0 = *(const short8*)(qp_ + (((u32)(J) * 128 +  0 + h16) ^ qswz)); \
    short8 b1 = *(const short8*)(qp_ + (((u32)(J) * 128 + 32 + h16) ^ qswz)); \
    short8 b2 = *(const short8*)(qp_ + (((u32)(J) * 128 + 64 + h16) ^ qswz)); \
    short8 b3 = *(const short8*)(qp_ + (((u32)(J) * 128 + 96 + h16) ^ qswz)); \
    __builtin_amdgcn_s_setprio(1);                                            \
    sacc = __builtin_amdgcn_mfma_f32_32x32x16_bf16(A0, b0, sacc, 0, 0, 0);    \
    sacc = __builtin_amdgcn_mfma_f32_32x32x16_bf16(A1, b1, sacc, 0, 0, 0);    \
    sacc = __builtin_amdgcn_mfma_f32_32x32x16_bf16(A2, b2, sacc, 0, 0, 0);    \
    sacc = __builtin_amdgcn_mfma_f32_32x32x16_bf16(A3, b3, sacc, 0, 0, 0);    \
    __builtin_amdgcn_s_setprio(0);                                            \
  } while (0)

  #define PV4(A0, A1, A2, A3, ACC) do {                                       \
    __builtin_amdgcn_s_setprio(1);                                            \
    ACC = __builtin_amdgcn_mfma_f32_32x32x16_bf16(A0, p0, ACC, 0, 0, 0);      \
    ACC = __builtin_amdgcn_mfma_f32_32x32x16_bf16(A1, p1, ACC, 0, 0, 0);      \
    ACC = __builtin_amdgcn_mfma_f32_32x32x16_bf16(A2, p2, ACC, 0, 0, 0);      \
    ACC = __builtin_amdgcn_mfma_f32_32x32x16_bf16(A3, p3, ACC, 0, 0, 0);      \
    __builtin_amdgcn_s_setprio(0);                                            \
  } while (0)

  for (int mkt = 0; mkt < NMKT; ++mkt) {
    const int cb = mkt * 32;

    // ------------- S^T = K Q^T over d=1024 (16 phases, no barriers) -------------
    // 4-buffer rotation: phase p computes buf[p&3], loads chunk p+3 into buf[(p+3)&3].
    #pragma unroll
    for (int jj = 0; jj < 16; jj += 4) {
      LOADF(fD0, fD1, fD2, fD3, cb + jj + 3);  QK4(fA0, fA1, fA2, fA3, jj + 0);
      LOADF(fA0, fA1, fA2, fA3, cb + jj + 4);  QK4(fB0, fB1, fB2, fB3, jj + 1);
      LOADF(fB0, fB1, fB2, fB3, cb + jj + 5);  QK4(fC0, fC1, fC2, fC3, jj + 2);
      LOADF(fC0, fC1, fC2, fC3, cb + jj + 6);  QK4(fD0, fD1, fD2, fD3, jj + 3);
    }
    // end state: fA=chunk cb+16 (V0), fB=cb+17, fC=cb+18

    // ---------------- in-register online softmax (R4-verified) ----------------
    float mx = sacc[0];
    #pragma unroll
    for (int i = 1; i < 16; i++) mx = fmaxf(mx, sacc[i]);
    mx = fmaxf(mx, __shfl_xor(mx, 32));
    if (lane < 32) sMx[w][lane] = mx;
    __syncthreads();
    float m_kt = sMx[0][q];
    #pragma unroll
    for (int w2 = 1; w2 < 8; ++w2) m_kt = fmaxf(m_kt, sMx[w2][q]);
    const float m_new = fmaxf(m_prev, m_kt);
    const float al = __expf(m_prev - m_new);   // 0 on first tile
    m_prev = m_new;
    float sum = 0.0f;
    #pragma unroll
    for (int i = 0; i < 16; i++) {
      float p = __expf(sacc[i] - m_new);
      sacc[i] = p;
      sum += p;
    }
    sum += __shfl_xor(sum, 32);
    if (lane < 32) sLs[w][lane] = sum;
    // P -> bf16 -> sP[q][kv]; lane's C rows: kv_local = (r&3)+8*(r>>2)+4h
    #pragma unroll
    for (int g = 0; g < 4; ++g) {
      ushort4 pk = { f2bf(sacc[4*g+0]), f2bf(sacc[4*g+1]),
                     f2bf(sacc[4*g+2]), f2bf(sacc[4*g+3]) };
      const u32 kvb = (u32)(w * 32 + g * 8 + h * 4);
      *(ushort4*)&sP[q * 256 + (kvb ^ ((q & 7) << 3))] = pk;
    }
    #pragma unroll
    for (int i = 0; i < 16; i++) { acc0[i] *= al; acc1[i] *= al; acc2[i] *= al; acc3[i] *= al; }
    __syncthreads();   // sP + sLs ready
    float l_kt = sLs[0][q];
    #pragma unroll
    for (int w2 = 1; w2 < 8; ++w2) l_kt += sLs[w2][q];
    l_prev = l_prev * al + l_kt;
    sacc = (floatx16)0.0f;

    // ------- O^T += V^T P^T (4 kvq x 4 dsl phases, no barriers) -------
    #pragma unroll
    for (int kvq = 0; kvq < 4; ++kvq) {
      const char* pp_ = (const char*)sP + prow;
      short8 p0 = *(const short8*)(pp_ + (((u32)kvq * 128 +  0 + h16) ^ qswz));
      short8 p1 = *(const short8*)(pp_ + (((u32)kvq * 128 + 32 + h16) ^ qswz));
      short8 p2 = *(const short8*)(pp_ + (((u32)kvq * 128 + 64 + h16) ^ qswz));
      short8 p3 = *(const short8*)(pp_ + (((u32)kvq * 128 + 96 + h16) ^ qswz));
      const int vc = cb + 16 + kvq * 4;
      LOADF(fD0, fD1, fD2, fD3, vc + 3);  PV4(fA0, fA1, fA2, fA3, acc0);
      LOADF(fA0, fA1, fA2, fA3, vc + 4);  PV4(fB0, fB1, fB2, fB3, acc1);
      LOADF(fB0, fB1, fB2, fB3, vc + 5);  PV4(fC0, fC1, fC2, fC3, acc2);
      LOADF(fC0, fC1, fC2, fC3, vc + 6);  PV4(fD0, fD1, fD2, fD3, acc3);
    }
    // end state: fA=next K chunk 0, fB=+1, fC=+2 (seamless into next mkt)
  }

  // ---------------- epilogue: O = acc^T / l (R4-verified) ----------------
  const float rinv = 1.0f / l_prev;
  const size_t orow = (size_t)(batch * SEQ + q0 + q) * DMODEL;
  #define STORE_TILE(ACC, DSL) do {                                           \
    _Pragma("unroll")                                                         \
    for (int g = 0; g < 4; ++g) {                                             \
      float4 o = { ACC[4*g+0]*rinv, ACC[4*g+1]*rinv,                          \
                   ACC[4*g+2]*rinv, ACC[4*g+3]*rinv };                        \
      *(float4*)&Og[orow + (DSL) * 256 + w * 32 + g * 8 + h * 4] = o;         \
    }                                                                         \
  } while (0)
  STORE_TILE(acc0, 0);
  STORE_TILE(acc1, 1);
  STORE_TILE(acc2, 2);
  STORE_TILE(acc3, 3);
  #undef STORE_TILE
  #undef PV4
  #undef QK4
  #undef LOADF
}

// ===================== fallback (verified round-1 kernel) ====================
__global__ __launch_bounds__(NTHREADS, 2)
void fa_fwd_fb(const float* __restrict__ Qg,
               const float* __restrict__ Kg,
               const float* __restrict__ Vg,
               float* __restrict__ Og) {
  __shared__ __align__(16) u16   sQ[32][1032];
  __shared__ __align__(16) u16   sK[64][264];
  __shared__ __align__(16) float sS[32][66];
  __shared__ __align__(16) u16   sP[32][72];
  __shared__ float sM[32], sL[32], sAl[32];

  const int tid = threadIdx.x, w = tid >> 6, lane = tid & 63;
  const int quad = lane >> 4, l15 = lane & 15;
  const int batch = blockIdx.y, q0 = blockIdx.x * 32;
  const size_t qbase  = (size_t)(batch * SEQ + q0) * DMODEL;
  const size_t kvbase = (size_t)batch * SEQ * DMODEL;
  if (tid < 32) { sM[tid] = -1e30f; sL[tid] = 0.0f; }
  #pragma unroll
  for (int i = 0; i < 16; i++) {
    const int e = tid + i * NTHREADS, row = e >> 8, c4 = (e & 255) << 2;
    float4 v = *(const float4*)&Qg[qbase + (size_t)row * DMODEL + c4];
    ushort4 pk = { f2bf(v.x), f2bf(v.y), f2bf(v.z), f2bf(v.w) };
    *(ushort4*)&sQ[row][c4] = pk;
  }
  floatx4 acc[2][8];
  #pragma unroll
  for (int rt = 0; rt < 2; rt++)
    #pragma unroll
    for (int ci = 0; ci < 8; ci++) acc[rt][ci] = (floatx4)0.0f;
  const int wr = w >> 2, wc = w & 3;
  for (int kt = 0; kt < SEQ / 64; kt++) {
    floatx4 sacc = (floatx4)0.0f;
    for (int dc = 0; dc < 4; dc++) {
      __syncthreads();
      #pragma unroll
      for (int i = 0; i < 8; i++) {
        const int e = tid + i * NTHREADS, row = e >> 6, c4 = (e & 63) << 2;
        float4 v = *(const float4*)&Kg[kvbase + (size_t)(kt * 64 + row) * DMODEL + dc * 256 + c4];
        ushort4 pk = { f2bf(v.x), f2bf(v.y), f2bf(v.z), f2bf(v.w) };
        *(ushort4*)&sK[row][c4] = pk;
      }
      __syncthreads();
      #pragma unroll
      for (int ks = 0; ks < 8; ks++) {
        short8 av = *(const short8*)&sQ[wr * 16 + l15][dc * 256 + ks * 32 + quad * 8];
        short8 bv = *(const short8*)&sK[wc * 16 + l15][ks * 32 + quad * 8];
        sacc = __builtin_amdgcn_mfma_f32_16x16x32_bf16(av, bv, sacc, 0, 0, 0);
      }
    }
    #pragma unroll
    for (int r = 0; r < 4; r++)
      sS[wr * 16 + quad * 4 + r][wc * 16 + l15] = sacc[r];
    __syncthreads();
    {
      const int row = tid >> 4, c0 = tid & 15;
      float v0 = sS[row][c0] * SCALE, v1 = sS[row][c0 + 16] * SCALE;
      float v2 = sS[row][c0 + 32] * SCALE, v3 = sS[row][c0 + 48] * SCALE;
      float mx = fmaxf(fmaxf(v0, v1), fmaxf(v2, v3));
      #pragma unroll
      for (int off = 8; off >= 1; off >>= 1) mx = fmaxf(mx, __shfl_xor(mx, off, 16));
      const float m_old = sM[row], m_new = fmaxf(m_old, mx);
      const float p0 = __expf(v0 - m_new), p1 = __expf(v1 - m_new);
      const float p2 = __expf(v2 - m_new), p3 = __expf(v3 - m_new);
      sP[row][c0] = f2bf(p0); sP[row][c0 + 16] = f2bf(p1);
      sP[row][c0 + 32] = f2bf(p2); sP[row][c0 + 48] = f2bf(p3);
      float sum = p0 + p1 + p2 + p3;
      #pragma unroll
      for (int off = 8; off >= 1; off >>= 1) sum += __shfl_xor(sum, off, 16);
      if (c0 == 0) {
        const float al = __expf(m_old - m_new);
        sAl[row] = al; sM[row] = m_new; sL[row] = sL[row] * al + sum;
      }
    }
    __syncthreads();
    float alv[2][4];
    #pragma unroll
    for (int rt = 0; rt < 2; rt++)
      #pragma unroll
      for (int r = 0; r < 4; r++) alv[rt][r] = sAl[rt * 16 + quad * 4 + r];
    #pragma unroll
    for (int rt = 0; rt < 2; rt++)
      #pragma unroll
      for (int ci = 0; ci < 8; ci++)
        #pragma unroll
        for (int r = 0; r < 4; r++) acc[rt][ci][r] *= alv[rt][r];
    #pragma unroll
    for (int ks = 0; ks < 2; ks++) {
      short8 a0 = *(const short8*)&sP[l15][ks * 32 + quad * 8];
      short8 a1 = *(const short8*)&sP[16 + l15][ks * 32 + quad * 8];
      #pragma unroll
      for (int ci = 0; ci < 8; ci++) {
        const int col = ((ci << 3) + w) * 16 + l15;
        const float* vp = Vg + kvbase + (size_t)(kt * 64 + ks * 32 + quad * 8) * DMODEL + col;
        short8 bv;
        #pragma unroll
        for (int j = 0; j < 8; j++) bv[j] = (short)f2bf(vp[(size_t)j * DMODEL]);
        acc[0][ci] = __builtin_amdgcn_mfma_f32_16x16x32_bf16(a0, bv, acc[0][ci], 0, 0, 0);
        acc[1][ci] = __builtin_amdgcn_mfma_f32_16x16x32_bf16(a1, bv, acc[1][ci], 0, 0, 0);
      }
    }
  }
  float linv[2][4];
  #pragma unroll
  for (int rt = 0; rt < 2; rt++)
    #pragma unroll
    for (int r = 0; r < 4; r++) linv[rt][r] = 1.0f / sL[rt * 16 + quad * 4 + r];
  #pragma unroll
  for (int rt = 0; rt < 2; rt++)
    #pragma unroll
    for (int ci = 0; ci < 8; ci++) {
      const int col = ((ci << 3) + w) * 16 + l15;
      #pragma unroll
      for (int r = 0; r < 4; r++) {
        const int row = q0 + rt * 16 + quad * 4 + r;
        Og[(size_t)(batch * SEQ + row) * DMODEL + col] = acc[rt][ci][r] * linv[rt][r];
      }
    }
}

extern "C" void kernel_launch(void* const* d_in, const int* in_sizes, int n_in,
                              void* d_out, int out_size, void* d_ws, size_t ws_size,
                              hipStream_t stream) {
  const float* Q = (const float*)d_in[0];
  const float* K = (const float*)d_in[1];
  const float* V = (const float*)d_in[2];
  float* O = (float*)d_out;
  const size_t wneed = (size_t)NBATCH * NCHB * 32768;   // 64 MB
  if (ws_size >= wneed) {
    u16* Wws = (u16*)d_ws;
    conv_k<<<dim3(SEQ, NBATCH), 256, 0, stream>>>(K, Wws);
    conv_v<<<dim3(SEQ / 32, DMODEL / 256, NBATCH), 256, 0, stream>>>(V, Wws);
    fa_fwd6<<<dim3(512), NTHREADS, 0, stream>>>(Q, Wws, O);
  } else {
    fa_fwd_fb<<<dim3(SEQ / 32, NBATCH), NTHREADS, 0, stream>>>(Q, K, V, O);
  }
}